// Round 17
// baseline (334.005 us; speedup 1.0000x reference)
//
#include <hip/hip_runtime.h>
#include <hip/hip_bf16.h>

typedef unsigned short u16;
typedef unsigned int u32;
typedef __attribute__((ext_vector_type(8))) short short8;
typedef __attribute__((ext_vector_type(4))) float f32x4;
typedef __attribute__((ext_vector_type(8))) unsigned short us8;
typedef __attribute__((ext_vector_type(4))) unsigned short us4;

#define S_LEN 2048
#define NH 32
#define NKV 4
#define HEAD 128
#define NQKV 9216  // 8192 (q+gate) + 512 (k) + 512 (v)

__device__ inline float b2f(u16 u) {
    union { unsigned int i; float f; } x; x.i = ((unsigned int)u) << 16; return x.f;
}
__device__ inline u16 f2b(float f) {
    __hip_bfloat16 h = __float2bfloat16(f);
    u16 u; __builtin_memcpy(&u, &h, 2); return u;
}
__device__ inline void async_copy16(const void* g, void* l) {
    __builtin_amdgcn_global_load_lds((const __attribute__((address_space(1))) void*)g,
                                     (__attribute__((address_space(3))) void*)l, 16, 0, 0);
}
// inline dtype detection: 64-lane ballot over samples.
__device__ inline int dtype_f32(const u16* hs) {
    int lane = threadIdx.x & 63;
    u16 v = hs[2 * (lane * 32)];
    int e = (v >> 7) & 0xFF;
    unsigned long long b = __ballot(e >= 0x90);
    return __popcll(b) > 16;
}
__device__ inline int dtype_i64(const u32* ng) {
    int lane = threadIdx.x & 63;
    unsigned long long b = __ballot(ng[2 * lane + 1] == 0);
    return __popcll(b) > 48;
}
// swizzled byte offset inside a [rows][128]-bf16 LDS tile (256 B rows)
__device__ inline int swzoff(int row, int kbyte) { return row * 256 + (kbyte ^ ((row & 7) << 4)); }

#define WAITV(n) asm volatile("s_waitcnt vmcnt(" #n ")" ::: "memory")
#define WAITL()  asm volatile("s_waitcnt lgkmcnt(0)" ::: "memory")
#define BAR()    do { __builtin_amdgcn_sched_barrier(0); __builtin_amdgcn_s_barrier(); \
                      __builtin_amdgcn_sched_barrier(0); } while (0)

// ---------------- ONE prep kernel: conv_hs | conv_small | all transposes | counter zero ----------------
__global__ __launch_bounds__(256) void prep_k(const void* __restrict__ hs,
                                              const void* __restrict__ cs, const void* __restrict__ sn,
                                              const void* __restrict__ qw, const void* __restrict__ kw,
                                              const void* __restrict__ Wq, const void* __restrict__ Wk,
                                              const void* __restrict__ Wv, const void* __restrict__ Wo,
                                              u16* __restrict__ HSB, u16* __restrict__ CSB, u16* __restrict__ SNB,
                                              u16* __restrict__ QWB, u16* __restrict__ KWB,
                                              u16* __restrict__ BT1, u16* __restrict__ WoT,
                                              int* __restrict__ cnt,
                                              const u16* __restrict__ hsamp) {
    int isf = dtype_f32(hsamp);
    int b = blockIdx.x;
    int tid = threadIdx.x;
    if (b == 0 && tid < 64) cnt[tid] = 0;         // split-K tile counters (every call)
    if (b < 2048) {                               // hidden: 8 elems/thread
        int i = b * 256 + tid;                    // us8 index, 524288 total
        if (isf) {
            f32x4 lo = ((const f32x4*)hs)[2 * i];
            f32x4 hi = ((const f32x4*)hs)[2 * i + 1];
            us8 o;
#pragma unroll
            for (int j = 0; j < 4; ++j) { o[j] = f2b(lo[j]); o[j + 4] = f2b(hi[j]); }
            ((us8*)HSB)[i] = o;
        } else {
            ((us8*)HSB)[i] = ((const us8*)hs)[i];
        }
        return;
    }
    if (b < 4098) {                               // small tables, scalar
        int i = (b - 2048) * 256 + tid;
        const void* s; u16* d; int off;
        if (i < 262144)      { s = cs; d = CSB; off = i; }
        else if (i < 524288) { s = sn; d = SNB; off = i - 262144; }
        else if (i < 524416) { s = qw; d = QWB; off = i - 524288; }
        else if (i < 524544) { s = kw; d = KWB; off = i - 524416; }
        else return;
        d[off] = isf ? f2b(((const float*)s)[off]) : ((const u16*)s)[off];
        return;
    }
    // transpose tiles
    int tb = b - 4098;
    __shared__ u16 t[64][68];
    const void* in; u16* out; int R, C, bx, by;
    if (tb < 4096)      { int q = tb;        in = Wq; out = BT1;                       R = 2048; C = 8192; bx = (q & 127) * 64; by = (q >> 7) * 64; }
    else if (tb < 4352) { int q = tb - 4096; in = Wk; out = BT1 + (size_t)8192 * 2048; R = 2048; C = 512;  bx = (q & 7) * 64;   by = (q >> 3) * 64; }
    else if (tb < 4608) { int q = tb - 4352; in = Wv; out = BT1 + (size_t)8704 * 2048; R = 2048; C = 512;  bx = (q & 7) * 64;   by = (q >> 3) * 64; }
    else                { int q = tb - 4608; in = Wo; out = WoT;                       R = 4096; C = 2048; bx = (q & 31) * 64;  by = (q >> 5) * 64; }
    if (isf) {
        int ch = tid & 15, r0 = tid >> 4;
#pragma unroll
        for (int p = 0; p < 4; ++p) {
            int r = r0 + p * 16;
            f32x4 v = *(const f32x4*)((const float*)in + (size_t)(by + r) * C + bx + ch * 4);
#pragma unroll
            for (int j = 0; j < 4; ++j) t[ch * 4 + j][r] = f2b(v[j]);
        }
    } else {
        int ch = tid & 7, r0 = tid >> 3;
#pragma unroll
        for (int p = 0; p < 2; ++p) {
            int r = r0 + p * 32;
            us8 v = *(const us8*)((const u16*)in + (size_t)(by + r) * C + bx + ch * 8);
#pragma unroll
            for (int j = 0; j < 8; ++j) t[ch * 8 + j][r] = v[j];
        }
    }
    __syncthreads();
    int ch = tid & 7, c0 = tid >> 3;
#pragma unroll
    for (int p = 0; p < 2; ++p) {
        int c = c0 + p * 32;
        us4 lo = *(const us4*)&t[c][ch * 8];
        us4 hi = *(const us4*)&t[c][ch * 8 + 4];
        u16* dst = out + (size_t)(bx + c) * R + by + ch * 8;
        *(us4*)dst = lo;
        *(us4*)(dst + 4) = hi;
    }
}

// ======== 256x256 8-phase GEMM (T2+T3+T4+T5): C = A[:, k0:k0+Keff] * Bt[:, k0:k0+Keff]^T ========
// 2D grid; split-K folded into x: bx = blockIdx.x % xtiles, bz = blockIdx.x / xtiles.
// k0 = bz*Keff; partials at Cc + bz*M*ldc. lda = row stride of A/Bt.
// FUSE: last-arriving z-block per (bx,by) tile sums the 4 bf16 partials -> f32 Fout (lookback pattern).
template <bool OUT_F32, bool FUSE>
__global__ __launch_bounds__(512, 2) void gemm_bt256(const u16* __restrict__ A, const u16* __restrict__ Bt,
                                                     void* __restrict__ Cc, int M, int Keff, int lda, int ldc,
                                                     int xtiles, float* __restrict__ Fout, int* __restrict__ cnt) {
    const int bx = blockIdx.x % xtiles, bz = blockIdx.x / xtiles, by = blockIdx.y;

    __shared__ __align__(16) char lds[131072];   // [buf][A 32K | B 32K]
    const int tid = threadIdx.x, lane = tid & 63, w = tid >> 6;
    const int wm = w >> 2, wn = w & 3;
    const int l15 = lane & 15, kg = lane >> 4;
    const int lr = lane >> 3, ls = lane & 7;
    const int m0 = by * 256, n0 = bx * 256;
    const int k0 = bz * Keff;

    f32x4 acc[8][4] = {};

    auto stA = [&](int b, int kt, int beta) {
#pragma unroll
        for (int i = 0; i < 2; ++i) {
            int row_in = w * 8 + lr;                       // 0..63
            int rg = i * 128 + (beta ? 64 : 0) + row_in;   // LDS/global row
            const u16* src = A + (size_t)(m0 + rg) * lda + k0 + kt + ((ls ^ (row_in & 7)) * 8);
            char* dst = lds + b * 65536 + i * 16384 + (beta ? 8192 : 0) + w * 1024;
            async_copy16(src, dst);
        }
    };
    auto stB = [&](int b, int kt, int beta) {
#pragma unroll
        for (int i = 0; i < 2; ++i) {
            int r32 = i * 2 + (w >> 2);                    // 0..3
            int row_in = (w & 3) * 8 + lr;                 // 0..31
            int rg = r32 * 64 + (beta ? 32 : 0) + row_in;
            const u16* src = Bt + (size_t)(n0 + rg) * lda + k0 + kt + ((ls ^ (row_in & 7)) * 8);
            char* dst = lds + b * 65536 + 32768 + r32 * 8192 + (beta ? 4096 : 0) + (w & 3) * 1024;
            async_copy16(src, dst);
        }
    };
    short8 af[4][2], bf[2][2];
    auto rdA = [&](int b, int mih) {
#pragma unroll
        for (int mi = 0; mi < 4; ++mi) {
            int row = wm * 128 + (mih * 4 + mi) * 16 + l15;
#pragma unroll
            for (int ks = 0; ks < 2; ++ks)
                af[mi][ks] = *(const short8*)(lds + b * 65536 + row * 128 +
                                              ((ks * 64 + kg * 16) ^ ((l15 & 7) << 4)));
        }
    };
    auto rdB = [&](int b, int nih) {
#pragma unroll
        for (int ni = 0; ni < 2; ++ni) {
            int row = wn * 64 + (nih * 2 + ni) * 16 + l15;
#pragma unroll
            for (int ks = 0; ks < 2; ++ks)
                bf[ni][ks] = *(const short8*)(lds + b * 65536 + 32768 + row * 128 +
                                              ((ks * 64 + kg * 16) ^ ((l15 & 7) << 4)));
        }
    };
    auto mm = [&](int mih, int nih) {
        __builtin_amdgcn_s_setprio(1);
#pragma unroll
        for (int ks = 0; ks < 2; ++ks)
#pragma unroll
            for (int mi = 0; mi < 4; ++mi)
#pragma unroll
                for (int ni = 0; ni < 2; ++ni)
                    acc[mih * 4 + mi][nih * 2 + ni] = __builtin_amdgcn_mfma_f32_16x16x32_bf16(
                        af[mi][ks], bf[ni][ks], acc[mih * 4 + mi][nih * 2 + ni], 0, 0, 0);
        __builtin_amdgcn_s_setprio(0);
        __builtin_amdgcn_sched_barrier(0);
    };

    // prologue: tile 0 -> buf 0
    stA(0, 0, 0); stB(0, 0, 0); stB(0, 0, 1); stA(0, 0, 1);
    WAITV(4); BAR();

    const int NT = Keff >> 6;
    for (int t = 0; t < NT - 1; ++t) {
        const int b = t & 1, nb = b ^ 1;
        const int kn = (t + 1) << 6;
        // p0
        rdA(b, 0); rdB(b, 0);
        stA(nb, kn, 0); stB(nb, kn, 0);
        WAITL(); WAITV(6); BAR();
        mm(0, 0);
        // p1
        rdB(b, 1);
        stB(nb, kn, 1);
        WAITL(); WAITV(6); BAR();
        mm(0, 1);
        // p2
        rdA(b, 1);
        stA(nb, kn, 1);
        WAITL(); BAR();
        mm(1, 1);
        // p3
        rdB(b, 0);
        WAITL(); WAITV(4); BAR();
        mm(1, 0);
    }
    {   // tail tile
        const int b = (NT - 1) & 1;
        rdA(b, 0); rdB(b, 0);
        WAITL(); WAITV(2); BAR();
        mm(0, 0);
        rdB(b, 1);
        WAITL(); WAITV(0); BAR();
        mm(0, 1);
        rdA(b, 1);
        WAITL(); BAR();
        mm(1, 1);
        rdB(b, 0);
        WAITL(); BAR();
        mm(1, 0);
    }

    // C/D layout: col = lane&15, row = (lane>>4)*4 + r   [m89-verified]
    size_t zoff = (size_t)bz * M * ldc;
#pragma unroll
    for (int mi = 0; mi < 8; ++mi) {
        int row_b = m0 + wm * 128 + mi * 16 + (lane >> 4) * 4;
#pragma unroll
        for (int ni = 0; ni < 4; ++ni) {
            int col = n0 + wn * 64 + ni * 16 + l15;
#pragma unroll
            for (int r = 0; r < 4; ++r) {
                size_t idx = zoff + (size_t)(row_b + r) * ldc + col;
                if (OUT_F32) ((float*)Cc)[idx] = acc[mi][ni][r];
                else         ((u16*)Cc)[idx] = f2b(acc[mi][ni][r]);
            }
        }
    }

    if (FUSE) {
        // release: make this block's partial visible device-wide, then count arrival
        __threadfence();
        __syncthreads();
        __shared__ int lastf;
        if (tid == 0) lastf = (atomicAdd(&cnt[by * xtiles + bx], 1) == 3);
        __syncthreads();
        if (lastf) {
            __threadfence();   // acquire: invalidate stale L2 before reading peers' partials
            const size_t stride = (size_t)M * ldc;
            const u16* Pp = (const u16*)Cc;
#pragma unroll
            for (int c = 0; c < 16; ++c) {
                int e = (c * 512 + tid) * 8;          // elem in 256x256 tile
                int rr = e >> 8, cc2 = e & 255;
                size_t base = (size_t)(m0 + rr) * ldc + n0 + cc2;
                us8 p0 = *(const us8*)(Pp + base);
                us8 p1 = *(const us8*)(Pp + stride + base);
                us8 p2 = *(const us8*)(Pp + 2 * stride + base);
                us8 p3 = *(const us8*)(Pp + 3 * stride + base);
                f32x4 lo, hi;
#pragma unroll
                for (int j = 0; j < 4; ++j) {
                    lo[j] = b2f(p0[j]) + b2f(p1[j]) + b2f(p2[j]) + b2f(p3[j]);
                    hi[j] = b2f(p0[j + 4]) + b2f(p1[j + 4]) + b2f(p2[j + 4]) + b2f(p3[j + 4]);
                }
                *(f32x4*)(Fout + base) = lo;
                *(f32x4*)(Fout + base + 4) = hi;
            }
        }
    }
}

// ---------------- 128x128 min-2-phase GEMM (lda/ldc-aware) ----------------
template <bool OUT_F32>
__global__ __launch_bounds__(256) void gemm_bt(const u16* __restrict__ A, const u16* __restrict__ Bt,
                                               void* __restrict__ Cc, int M, int K, int lda, int ldc) {
    __shared__ __align__(16) u16 As[2][128][32];
    __shared__ __align__(16) u16 Bs[2][128][32];
    int tid = threadIdx.x, lane = tid & 63, wv = tid >> 6;
    int wm = wv >> 1, wn = wv & 1;
    int m0 = blockIdx.y * 128, n0 = blockIdx.x * 128;
    int l15 = lane & 15, kg = lane >> 4;

    auto STAGE = [&](int buf, int kt) {
#pragma unroll
        for (int p = 0; p < 2; ++p) {
            int base = (p * 4 + wv) * 64;
            int unit = base + lane;
            int row = unit >> 2, ce = (unit & 3) << 3;
            async_copy16(A + (size_t)(m0 + row) * lda + kt + ce,
                         (char*)&As[buf][0][0] + (size_t)base * 16);
            async_copy16(Bt + (size_t)(n0 + row) * lda + kt + ce,
                         (char*)&Bs[buf][0][0] + (size_t)base * 16);
        }
    };

    f32x4 acc[4][4];
#pragma unroll
    for (int mi = 0; mi < 4; ++mi)
#pragma unroll
        for (int ni = 0; ni < 4; ++ni)
            acc[mi][ni] = (f32x4){0.f, 0.f, 0.f, 0.f};

    STAGE(0, 0);
    __syncthreads();
    int cur = 0;
    for (int kt = 0; kt < K; kt += 32) {
        if (kt + 32 < K) STAGE(cur ^ 1, kt + 32);

        short8 af[4], bfr[4];
#pragma unroll
        for (int mi = 0; mi < 4; ++mi)
            af[mi] = *(const short8*)&As[cur][wm * 64 + mi * 16 + l15][kg * 8];
#pragma unroll
        for (int ni = 0; ni < 4; ++ni)
            bfr[ni] = *(const short8*)&Bs[cur][wn * 64 + ni * 16 + l15][kg * 8];
#pragma unroll
        for (int mi = 0; mi < 4; ++mi)
#pragma unroll
            for (int ni = 0; ni < 4; ++ni)
                acc[mi][ni] = __builtin_amdgcn_mfma_f32_16x16x32_bf16(af[mi], bfr[ni], acc[mi][ni], 0, 0, 0);

        __syncthreads();
        cur ^= 1;
    }

#pragma unroll
    for (int mi = 0; mi < 4; ++mi) {
        int row_b = m0 + wm * 64 + mi * 16 + (lane >> 4) * 4;
#pragma unroll
        for (int ni = 0; ni < 4; ++ni) {
            int col = n0 + wn * 64 + ni * 16 + l15;
#pragma unroll
            for (int r = 0; r < 4; ++r) {
                size_t idx = (size_t)(row_b + r) * ldc + col;
                if (OUT_F32) ((float*)Cc)[idx] = acc[mi][ni][r];
                else         ((u16*)Cc)[idx] = f2b(acc[mi][ni][r]);
            }
        }
    }
}

// ---------------- RMSNorm + RoPE, 16 threads/head-unit, no LDS/barriers ----------------
__global__ __launch_bounds__(256) void norm_rope2(const u16* __restrict__ qkv,
                                                  const u16* __restrict__ qw, const u16* __restrict__ kw,
                                                  const u16* __restrict__ cosp, const u16* __restrict__ sinp,
                                                  u16* __restrict__ qr, u16* __restrict__ kr) {
    int t = threadIdx.x;
    int unit = blockIdx.x * 16 + (t >> 4);
    int lt = t & 15;
    int s = unit / 36, u = unit - s * 36;
    int d0 = lt * 8;

    size_t src;
    if (u < 32) src = (size_t)s * NQKV + u * 256 + d0;
    else        src = (size_t)s * NQKV + 8192 + (u - 32) * 128 + d0;
    us8 xv = *(const us8*)(qkv + src);
    float x[8];
    float ss = 0.f;
#pragma unroll
    for (int i = 0; i < 8; ++i) { x[i] = b2f(xv[i]); ss += x[i] * x[i]; }
#pragma unroll
    for (int m = 1; m <= 8; m <<= 1) ss += __shfl_xor(ss, m);
    float rms = rsqrtf(ss * (1.0f / 128.0f) + 1e-6f);

    const u16* wp = (u < 32 ? qw : kw) + d0;
    us8 wv8 = *(const us8*)wp;
    float xn[8];
#pragma unroll
    for (int i = 0; i < 8; ++i) xn[i] = x[i] * rms * b2f(wv8[i]);

    float rot[8];
#pragma unroll
    for (int i = 0; i < 8; ++i) {
        float other = __shfl_xor(xn[i], 8);
        rot[i] = (lt < 8) ? -other : other;
    }
    us8 cv = *(const us8*)(cosp + s * 128 + d0);
    us8 sv = *(const us8*)(sinp + s * 128 + d0);
    us8 o;
#pragma unroll
    for (int i = 0; i < 8; ++i)
        o[i] = f2b(xn[i] * b2f(cv[i]) + rot[i] * b2f(sv[i]));

    if (u < 32) *(us8*)(qr + ((size_t)s * NH + u) * 128 + d0) = o;
    else        *(us8*)(kr + ((size_t)(u - 32) * S_LEN + s) * 128 + d0) = o;
}

// ---------------- neighbor attention + sigmoid gate (MFMA, v3: 37KB LDS, 4 blocks/CU) ----------------
__global__ __launch_bounds__(256) void attn_k(const u16* __restrict__ qr, const u16* __restrict__ kr,
                                              const u16* __restrict__ qkv, const void* __restrict__ ngv,
                                              u16* __restrict__ A2) {
    int s = blockIdx.x, kv = blockIdx.y;
    int t = threadIdx.x, wv = t >> 6, lane = t & 63;
    int h16 = lane & 15, kg = lane >> 4;
    int isi64 = dtype_i64((const u32*)ngv);

    __shared__ __align__(16) char KVb[32768];   // K tile -> (Sc f32) -> V^T tile
    __shared__ __align__(16) u16 Ps[16 * 128];
    __shared__ int sidx[128];
    __shared__ float svalid[128];
    float* Sc = (float*)KVb;                    // [128][17] f32 = 8704 B, aliases K

    if (t < 128) {
        int idx;
        if (isi64) idx = (int)((const long long*)ngv)[(size_t)s * 128 + t];
        else       idx = ((const int*)ngv)[s * 128 + t];
        bool valid = (idx >= 0) && (idx <= s);
        int safe = idx < 0 ? 0 : (idx > S_LEN - 1 ? S_LEN - 1 : idx);
        sidx[t] = safe;
        svalid[t] = valid ? 1.f : 0.f;
    }
    ((us4*)Ps)[256 + t] = (us4){0, 0, 0, 0};   // zero pad rows 8..15 of P
    __syncthreads();                            // bar0: sidx ready

    // ---- stage K via global_load_lds (linear dest, pre-swizzled source column) ----
#pragma unroll
    for (int it = 0; it < 8; ++it) {
        int c = it * 256 + t;
        int j = c >> 4, slot = c & 15;
        const u16* src = kr + ((size_t)kv * S_LEN + sidx[j]) * 128 + ((slot ^ (j & 7)) * 8);
        async_copy16(src, KVb + c * 16);
    }
    const u16* qbase = qr + ((size_t)s * NH + kv * 8 + (h16 & 7)) * HEAD;
    short8 qf[4];
#pragma unroll
    for (int kk = 0; kk < 4; ++kk)
        qf[kk] = *(const short8*)(qbase + kk * 32 + kg * 8);
    __syncthreads();                            // bar1: K in LDS, Q in regs

    // ---- issue V gather (d-major, wave-uniform row, coalesced) + gate prefetch; hide under QK^T ----
    us8 vreg[8];
#pragma unroll
    for (int it = 0; it < 8; ++it) {
        int task = it * 256 + t;
        int d = task & 127, jg = task >> 7;
        const u16* vbase = qkv + 8704 + kv * 128 + d;
#pragma unroll
        for (int k = 0; k < 8; ++k)
            vreg[it][k] = vbase[(size_t)sidx[jg * 8 + k] * NQKV];
    }
    u16 greg[8];
    if (kg < 2) {
#pragma unroll
        for (int tt = 0; tt < 2; ++tt)
#pragma unroll
            for (int r = 0; r < 4; ++r)
                greg[tt * 4 + r] = qkv[(size_t)s * NQKV + (kv * 8 + kg * 4 + r) * 256 + 128 +
                                       (wv * 2 + tt) * 16 + h16];
    }

    // ---- QK^T: accumulators stay in regs (Sc aliases K; no LDS writes yet) ----
    const float scale = 0.08838834764831845f;  // 1/sqrt(128)
    f32x4 aq[2];
#pragma unroll
    for (int tt = 0; tt < 2; ++tt) {
        int nt = wv * 2 + tt;
        f32x4 a = (f32x4){0.f, 0.f, 0.f, 0.f};
#pragma unroll
        for (int kk = 0; kk < 4; ++kk) {
            short8 kf = *(const short8*)(KVb + swzoff(nt * 16 + h16, kk * 64 + kg * 16));
            a = __builtin_amdgcn_mfma_f32_16x16x32_bf16(kf, qf[kk], a, 0, 0, 0);
        }
        aq[tt] = a;
    }
    __syncthreads();                            // bar2: all K reads done (drains V+gate loads too)

    // ---- write scores over the dead K region ----
#pragma unroll
    for (int tt = 0; tt < 2; ++tt) {
        int nt = wv * 2 + tt;
#pragma unroll
        for (int r = 0; r < 4; ++r) {
            int j = nt * 16 + kg * 4 + r;
            Sc[j * 17 + h16] = (svalid[j] > 0.f) ? aq[tt][r] * scale : -1e9f;
        }
    }
    __syncthreads();                            // bar3: Sc visible

    // ---- wave-parallel softmax -> Ps ----
    {
        int h = t >> 5, g = t & 31;
        float sv[4];
#pragma unroll
        for (int q = 0; q < 4; ++q) sv[q] = Sc[(g + 32 * q) * 17 + h];
        float m = fmaxf(fmaxf(sv[0], sv[1]), fmaxf(sv[2], sv[3]));
#pragma unroll
        for (int o = 16; o; o >>= 1) m = fmaxf(m, __shfl_xor(m, o));
        float e0 = __expf(sv[0] - m), e1 = __expf(sv[1] - m);
        float e2 = __expf(sv[2] - m), e3 = __expf(sv[3] - m);
        float sum = e0 + e1 + e2 + e3;
#pragma unroll
        for (int o = 16; o; o >>= 1) sum += __shfl_xor(sum, o);
        float inv = 1.f / sum;
        *(u16*)((char*)Ps + swzoff(h, 2 * (g)))      = f2b(e0 * inv);
        *(u16*)((char*)Ps + swzoff(h, 2 * (g + 32))) = f2b(e1 * inv);
        *(u16*)((char*)Ps + swzoff(h, 2 * (g + 64))) = f2b(e2 * inv);
        *(u16*)((char*)Ps + swzoff(h, 2 * (g + 96))) = f2b(e3 * inv);
    }
    __syncthreads();                            // bar4: Ps visible; Sc reads done

    // ---- write V^T (swizzled; clobbers dead Sc) ----
#pragma unroll
    for (int it = 0; it < 8; ++it) {
        int task = it * 256 + t;
        int d = task & 127, jg = task >> 7;
        *(us8*)(KVb + swzoff(d, jg * 16)) = vreg[it];
    }
    __syncthreads();                            // bar5: V^T visible

    // ---- PV + gate ----
    short8 pf[4];
#pragma unroll
    for (int kk = 0; kk < 4; ++kk)
        pf[kk] = *(const short8*)((char*)Ps + swzoff(h16, kk * 64 + kg * 16));
#pragma unroll
    for (int tt = 0; tt < 2; ++tt) {
        int nt = wv * 2 + tt;
        f32x4 a = (f32x4){0.f, 0.f, 0.f, 0.f};
#pragma unroll
        for (int jj = 0; jj < 4; ++jj) {
            short8 vf = *(const short8*)(KVb + swzoff(nt * 16 + h16, jj * 64 + kg * 16));
            a = __builtin_amdgcn_mfma_f32_16x16x32_bf16(pf[jj], vf, a, 0, 0, 0);
        }
        int d = nt * 16 + h16;
        if (kg < 2) {
#pragma unroll
            for (int r = 0; r < 4; ++r) {
                int head = kv * 8 + kg * 4 + r;
                float gt = b2f(greg[tt * 4 + r]);
                float o = a[r] * (1.f / (1.f + __expf(-gt)));
                A2[((size_t)s * NH + head) * 128 + d] = f2b(o);
            }
        }
    }
}

extern "C" void kernel_launch(void* const* d_in, const int* in_sizes, int n_in,
                              void* d_out, int out_size, void* d_ws, size_t ws_size,
                              hipStream_t stream) {
    const void* hs = d_in[0];
    const void* Wq = d_in[1];
    const void* Wk = d_in[2];
    const void* Wv = d_in[3];
    const void* Wo = d_in[4];
    const void* qw = d_in[5];
    const void* kw = d_in[6];
    const void* cs = d_in[7];
    const void* sn = d_in[8];
    const void* ng = d_in[9];
    const u16* hsamp = (const u16*)hs;

    char* w = (char*)d_ws;
    u16* HSB = (u16*)w;
    u16* KR  = (u16*)w;
    u16* BT1 = (u16*)(w + 8388608ull);
    u16* QR  = (u16*)(w + 8388608ull);
    u16* A2  = (u16*)(w + 8388608ull + 16777216ull);
    u16* WoT = (u16*)(w + 46137344ull);
    u16* QKV = (u16*)(w + 62914560ull);            // dead after attn_k -> P (4x 8.4MB bf16 partials)
    u16* P   = QKV;
    u16* CSB = (u16*)(w + 100663296ull);
    u16* SNB = (u16*)(w + 100663296ull + 524288ull);
    u16* QWB = (u16*)(w + 100663296ull + 1048576ull);
    u16* KWB = (u16*)(w + 100663296ull + 1052672ull);
    int* CNT = (int*)(w + 100663296ull + 1056768ull);   // 64 split-K tile counters

    // one prep launch: hidden conv | small-table conv | all weight transposes | counter zero
    prep_k<<<10754, 256, 0, stream>>>(hs, cs, sn, qw, kw, Wq, Wk, Wv, Wo,
                                      HSB, CSB, SNB, QWB, KWB, BT1, WoT, CNT, hsamp);

    // GEMM1a: q+gate = hidden @ Wq (M=2048, N=8192, K=2048): 2D grid, 256 blocks = one 8ph round
    gemm_bt256<false, false><<<dim3(32, 8), 512, 0, stream>>>(HSB, BT1, QKV, 2048, 2048, 2048, NQKV, 32,
                                                              nullptr, nullptr);
    // GEMM1b: k,v = hidden @ [Wk|Wv] (M=2048, N=1024): 128 blocks of 2ph-128^2
    gemm_bt<false><<<dim3(1024 / 128, 2048 / 128), 256, 0, stream>>>(HSB, BT1 + (size_t)8192 * 2048,
                                                                     QKV + 8192, 2048, 2048, 2048, NQKV);

    // per-head RMSNorm + rotary (16 threads/unit, no LDS)
    norm_rope2<<<4608, 256, 0, stream>>>(QKV, QWB, KWB, CSB, SNB, QR, KR);

    // neighbor attention + sigmoid gate -> A2 [2048, 4096] bf16  (QKV dead after this)
    attn_k<<<dim3(2048, 4), 256, 0, stream>>>(QR, KR, QKV, ng, A2);

    // GEMM2: out = A2 @ Wo (M=2048, N=2048, K=4096): 8ph split-K=4, fused last-block reduction -> f32 d_out
    gemm_bt256<false, true><<<dim3(32, 8), 512, 0, stream>>>(A2, WoT, P, 2048, 1024, 4096, 2048, 8,
                                                             (float*)d_out, CNT);
}

// Round 18
// 241.773 us; speedup vs baseline: 1.3815x; 1.3815x over previous
//
#include <hip/hip_runtime.h>
#include <hip/hip_bf16.h>

typedef unsigned short u16;
typedef unsigned int u32;
typedef __attribute__((ext_vector_type(8))) short short8;
typedef __attribute__((ext_vector_type(4))) float f32x4;
typedef __attribute__((ext_vector_type(8))) unsigned short us8;
typedef __attribute__((ext_vector_type(4))) unsigned short us4;

#define S_LEN 2048
#define NH 32
#define NKV 4
#define HEAD 128
#define NQKV 9216  // 8192 (q+gate) + 512 (k) + 512 (v)

__device__ inline float b2f(u16 u) {
    union { unsigned int i; float f; } x; x.i = ((unsigned int)u) << 16; return x.f;
}
__device__ inline u16 f2b(float f) {
    __hip_bfloat16 h = __float2bfloat16(f);
    u16 u; __builtin_memcpy(&u, &h, 2); return u;
}
__device__ inline void async_copy16(const void* g, void* l) {
    __builtin_amdgcn_global_load_lds((const __attribute__((address_space(1))) void*)g,
                                     (__attribute__((address_space(3))) void*)l, 16, 0, 0);
}
// inline dtype detection: 64-lane ballot over samples.
__device__ inline int dtype_f32(const u16* hs) {
    int lane = threadIdx.x & 63;
    u16 v = hs[2 * (lane * 32)];
    int e = (v >> 7) & 0xFF;
    unsigned long long b = __ballot(e >= 0x90);
    return __popcll(b) > 16;
}
__device__ inline int dtype_i64(const u32* ng) {
    int lane = threadIdx.x & 63;
    unsigned long long b = __ballot(ng[2 * lane + 1] == 0);
    return __popcll(b) > 48;
}
// swizzled byte offset inside a [rows][128]-bf16 LDS tile (256 B rows)
__device__ inline int swzoff(int row, int kbyte) { return row * 256 + (kbyte ^ ((row & 7) << 4)); }

#define WAITV(n) asm volatile("s_waitcnt vmcnt(" #n ")" ::: "memory")
#define WAITL()  asm volatile("s_waitcnt lgkmcnt(0)" ::: "memory")
#define BAR()    do { __builtin_amdgcn_sched_barrier(0); __builtin_amdgcn_s_barrier(); \
                      __builtin_amdgcn_sched_barrier(0); } while (0)

// ---------------- ONE prep kernel: conv_hs | conv_small | all transposes ----------------
// blocks 0..2047: hidden f32/bf16 -> bf16 (us8, 8 elems/thread)
// blocks 2048..4097: cos|sin|qw|kw convert
// blocks 4098..10753: 64x64 transpose tiles (Wq | Wk | Wv | Wo)
__global__ __launch_bounds__(256) void prep_k(const void* __restrict__ hs,
                                              const void* __restrict__ cs, const void* __restrict__ sn,
                                              const void* __restrict__ qw, const void* __restrict__ kw,
                                              const void* __restrict__ Wq, const void* __restrict__ Wk,
                                              const void* __restrict__ Wv, const void* __restrict__ Wo,
                                              u16* __restrict__ HSB, u16* __restrict__ CSB, u16* __restrict__ SNB,
                                              u16* __restrict__ QWB, u16* __restrict__ KWB,
                                              u16* __restrict__ BT1, u16* __restrict__ WoT,
                                              const u16* __restrict__ hsamp) {
    int isf = dtype_f32(hsamp);
    int b = blockIdx.x;
    int tid = threadIdx.x;
    if (b < 2048) {                               // hidden: 8 elems/thread
        int i = b * 256 + tid;                    // us8 index, 524288 total
        if (isf) {
            f32x4 lo = ((const f32x4*)hs)[2 * i];
            f32x4 hi = ((const f32x4*)hs)[2 * i + 1];
            us8 o;
#pragma unroll
            for (int j = 0; j < 4; ++j) { o[j] = f2b(lo[j]); o[j + 4] = f2b(hi[j]); }
            ((us8*)HSB)[i] = o;
        } else {
            ((us8*)HSB)[i] = ((const us8*)hs)[i];
        }
        return;
    }
    if (b < 4098) {                               // small tables, scalar
        int i = (b - 2048) * 256 + tid;
        const void* s; u16* d; int off;
        if (i < 262144)      { s = cs; d = CSB; off = i; }
        else if (i < 524288) { s = sn; d = SNB; off = i - 262144; }
        else if (i < 524416) { s = qw; d = QWB; off = i - 524288; }
        else if (i < 524544) { s = kw; d = KWB; off = i - 524416; }
        else return;
        d[off] = isf ? f2b(((const float*)s)[off]) : ((const u16*)s)[off];
        return;
    }
    // transpose tiles
    int tb = b - 4098;
    __shared__ u16 t[64][68];
    const void* in; u16* out; int R, C, bx, by;
    if (tb < 4096)      { int q = tb;        in = Wq; out = BT1;                       R = 2048; C = 8192; bx = (q & 127) * 64; by = (q >> 7) * 64; }
    else if (tb < 4352) { int q = tb - 4096; in = Wk; out = BT1 + (size_t)8192 * 2048; R = 2048; C = 512;  bx = (q & 7) * 64;   by = (q >> 3) * 64; }
    else if (tb < 4608) { int q = tb - 4352; in = Wv; out = BT1 + (size_t)8704 * 2048; R = 2048; C = 512;  bx = (q & 7) * 64;   by = (q >> 3) * 64; }
    else                { int q = tb - 4608; in = Wo; out = WoT;                       R = 4096; C = 2048; bx = (q & 31) * 64;  by = (q >> 5) * 64; }
    if (isf) {
        int ch = tid & 15, r0 = tid >> 4;
#pragma unroll
        for (int p = 0; p < 4; ++p) {
            int r = r0 + p * 16;
            f32x4 v = *(const f32x4*)((const float*)in + (size_t)(by + r) * C + bx + ch * 4);
#pragma unroll
            for (int j = 0; j < 4; ++j) t[ch * 4 + j][r] = f2b(v[j]);
        }
    } else {
        int ch = tid & 7, r0 = tid >> 3;
#pragma unroll
        for (int p = 0; p < 2; ++p) {
            int r = r0 + p * 32;
            us8 v = *(const us8*)((const u16*)in + (size_t)(by + r) * C + bx + ch * 8);
#pragma unroll
            for (int j = 0; j < 8; ++j) t[ch * 8 + j][r] = v[j];
        }
    }
    __syncthreads();
    int ch = tid & 7, c0 = tid >> 3;
#pragma unroll
    for (int p = 0; p < 2; ++p) {
        int c = c0 + p * 32;
        us4 lo = *(const us4*)&t[c][ch * 8];
        us4 hi = *(const us4*)&t[c][ch * 8 + 4];
        u16* dst = out + (size_t)(bx + c) * R + by + ch * 8;
        *(us4*)dst = lo;
        *(us4*)(dst + 4) = hi;
    }
}

// ======== 256x256 8-phase GEMM (T2+T3+T4+T5): C = A[:, k0:k0+Keff] * Bt[:, k0:k0+Keff]^T ========
// 2D grid; split-K folded into x: bx = blockIdx.x % xtiles, bz = blockIdx.x / xtiles.
// k0 = bz*Keff; partials at Cc + bz*M*ldc. lda = row stride of A/Bt.
template <bool OUT_F32>
__global__ __launch_bounds__(512, 2) void gemm_bt256(const u16* __restrict__ A, const u16* __restrict__ Bt,
                                                     void* __restrict__ Cc, int M, int Keff, int lda, int ldc,
                                                     int xtiles) {
    const int bx = blockIdx.x % xtiles, bz = blockIdx.x / xtiles, by = blockIdx.y;

    __shared__ __align__(16) char lds[131072];   // [buf][A 32K | B 32K]
    const int tid = threadIdx.x, lane = tid & 63, w = tid >> 6;
    const int wm = w >> 2, wn = w & 3;
    const int l15 = lane & 15, kg = lane >> 4;
    const int lr = lane >> 3, ls = lane & 7;
    const int m0 = by * 256, n0 = bx * 256;
    const int k0 = bz * Keff;

    f32x4 acc[8][4] = {};

    auto stA = [&](int b, int kt, int beta) {
#pragma unroll
        for (int i = 0; i < 2; ++i) {
            int row_in = w * 8 + lr;                       // 0..63
            int rg = i * 128 + (beta ? 64 : 0) + row_in;   // LDS/global row
            const u16* src = A + (size_t)(m0 + rg) * lda + k0 + kt + ((ls ^ (row_in & 7)) * 8);
            char* dst = lds + b * 65536 + i * 16384 + (beta ? 8192 : 0) + w * 1024;
            async_copy16(src, dst);
        }
    };
    auto stB = [&](int b, int kt, int beta) {
#pragma unroll
        for (int i = 0; i < 2; ++i) {
            int r32 = i * 2 + (w >> 2);                    // 0..3
            int row_in = (w & 3) * 8 + lr;                 // 0..31
            int rg = r32 * 64 + (beta ? 32 : 0) + row_in;
            const u16* src = Bt + (size_t)(n0 + rg) * lda + k0 + kt + ((ls ^ (row_in & 7)) * 8);
            char* dst = lds + b * 65536 + 32768 + r32 * 8192 + (beta ? 4096 : 0) + (w & 3) * 1024;
            async_copy16(src, dst);
        }
    };
    short8 af[4][2], bf[2][2];
    auto rdA = [&](int b, int mih) {
#pragma unroll
        for (int mi = 0; mi < 4; ++mi) {
            int row = wm * 128 + (mih * 4 + mi) * 16 + l15;
#pragma unroll
            for (int ks = 0; ks < 2; ++ks)
                af[mi][ks] = *(const short8*)(lds + b * 65536 + row * 128 +
                                              ((ks * 64 + kg * 16) ^ ((l15 & 7) << 4)));
        }
    };
    auto rdB = [&](int b, int nih) {
#pragma unroll
        for (int ni = 0; ni < 2; ++ni) {
            int row = wn * 64 + (nih * 2 + ni) * 16 + l15;
#pragma unroll
            for (int ks = 0; ks < 2; ++ks)
                bf[ni][ks] = *(const short8*)(lds + b * 65536 + 32768 + row * 128 +
                                              ((ks * 64 + kg * 16) ^ ((l15 & 7) << 4)));
        }
    };
    auto mm = [&](int mih, int nih) {
        __builtin_amdgcn_s_setprio(1);
#pragma unroll
        for (int ks = 0; ks < 2; ++ks)
#pragma unroll
            for (int mi = 0; mi < 4; ++mi)
#pragma unroll
                for (int ni = 0; ni < 2; ++ni)
                    acc[mih * 4 + mi][nih * 2 + ni] = __builtin_amdgcn_mfma_f32_16x16x32_bf16(
                        af[mi][ks], bf[ni][ks], acc[mih * 4 + mi][nih * 2 + ni], 0, 0, 0);
        __builtin_amdgcn_s_setprio(0);
        __builtin_amdgcn_sched_barrier(0);
    };

    // prologue: tile 0 -> buf 0
    stA(0, 0, 0); stB(0, 0, 0); stB(0, 0, 1); stA(0, 0, 1);
    WAITV(4); BAR();

    const int NT = Keff >> 6;
    for (int t = 0; t < NT - 1; ++t) {
        const int b = t & 1, nb = b ^ 1;
        const int kn = (t + 1) << 6;
        // p0
        rdA(b, 0); rdB(b, 0);
        stA(nb, kn, 0); stB(nb, kn, 0);
        WAITL(); WAITV(6); BAR();
        mm(0, 0);
        // p1
        rdB(b, 1);
        stB(nb, kn, 1);
        WAITL(); WAITV(6); BAR();
        mm(0, 1);
        // p2
        rdA(b, 1);
        stA(nb, kn, 1);
        WAITL(); BAR();
        mm(1, 1);
        // p3
        rdB(b, 0);
        WAITL(); WAITV(4); BAR();
        mm(1, 0);
    }
    {   // tail tile
        const int b = (NT - 1) & 1;
        rdA(b, 0); rdB(b, 0);
        WAITL(); WAITV(2); BAR();
        mm(0, 0);
        rdB(b, 1);
        WAITL(); WAITV(0); BAR();
        mm(0, 1);
        rdA(b, 1);
        WAITL(); BAR();
        mm(1, 1);
        rdB(b, 0);
        WAITL(); BAR();
        mm(1, 0);
    }

    // C/D layout: col = lane&15, row = (lane>>4)*4 + r   [m89-verified]
    size_t zoff = (size_t)bz * M * ldc;
#pragma unroll
    for (int mi = 0; mi < 8; ++mi) {
        int row_b = m0 + wm * 128 + mi * 16 + (lane >> 4) * 4;
#pragma unroll
        for (int ni = 0; ni < 4; ++ni) {
            int col = n0 + wn * 64 + ni * 16 + l15;
#pragma unroll
            for (int r = 0; r < 4; ++r) {
                size_t idx = zoff + (size_t)(row_b + r) * ldc + col;
                if (OUT_F32) ((float*)Cc)[idx] = acc[mi][ni][r];
                else         ((u16*)Cc)[idx] = f2b(acc[mi][ni][r]);
            }
        }
    }
}

// ---------------- 128x128 min-2-phase GEMM (lda/ldc-aware) ----------------
template <bool OUT_F32>
__global__ __launch_bounds__(256) void gemm_bt(const u16* __restrict__ A, const u16* __restrict__ Bt,
                                               void* __restrict__ Cc, int M, int K, int lda, int ldc) {
    __shared__ __align__(16) u16 As[2][128][32];
    __shared__ __align__(16) u16 Bs[2][128][32];
    int tid = threadIdx.x, lane = tid & 63, wv = tid >> 6;
    int wm = wv >> 1, wn = wv & 1;
    int m0 = blockIdx.y * 128, n0 = blockIdx.x * 128;
    int l15 = lane & 15, kg = lane >> 4;

    auto STAGE = [&](int buf, int kt) {
#pragma unroll
        for (int p = 0; p < 2; ++p) {
            int base = (p * 4 + wv) * 64;
            int unit = base + lane;
            int row = unit >> 2, ce = (unit & 3) << 3;
            async_copy16(A + (size_t)(m0 + row) * lda + kt + ce,
                         (char*)&As[buf][0][0] + (size_t)base * 16);
            async_copy16(Bt + (size_t)(n0 + row) * lda + kt + ce,
                         (char*)&Bs[buf][0][0] + (size_t)base * 16);
        }
    };

    f32x4 acc[4][4];
#pragma unroll
    for (int mi = 0; mi < 4; ++mi)
#pragma unroll
        for (int ni = 0; ni < 4; ++ni)
            acc[mi][ni] = (f32x4){0.f, 0.f, 0.f, 0.f};

    STAGE(0, 0);
    __syncthreads();
    int cur = 0;
    for (int kt = 0; kt < K; kt += 32) {
        if (kt + 32 < K) STAGE(cur ^ 1, kt + 32);

        short8 af[4], bfr[4];
#pragma unroll
        for (int mi = 0; mi < 4; ++mi)
            af[mi] = *(const short8*)&As[cur][wm * 64 + mi * 16 + l15][kg * 8];
#pragma unroll
        for (int ni = 0; ni < 4; ++ni)
            bfr[ni] = *(const short8*)&Bs[cur][wn * 64 + ni * 16 + l15][kg * 8];
#pragma unroll
        for (int mi = 0; mi < 4; ++mi)
#pragma unroll
            for (int ni = 0; ni < 4; ++ni)
                acc[mi][ni] = __builtin_amdgcn_mfma_f32_16x16x32_bf16(af[mi], bfr[ni], acc[mi][ni], 0, 0, 0);

        __syncthreads();
        cur ^= 1;
    }

#pragma unroll
    for (int mi = 0; mi < 4; ++mi) {
        int row_b = m0 + wm * 64 + mi * 16 + (lane >> 4) * 4;
#pragma unroll
        for (int ni = 0; ni < 4; ++ni) {
            int col = n0 + wn * 64 + ni * 16 + l15;
#pragma unroll
            for (int r = 0; r < 4; ++r) {
                size_t idx = (size_t)(row_b + r) * ldc + col;
                if (OUT_F32) ((float*)Cc)[idx] = acc[mi][ni][r];
                else         ((u16*)Cc)[idx] = f2b(acc[mi][ni][r]);
            }
        }
    }
}

// ---------------- reduce 4 bf16 split-K partials -> f32 d_out ----------------
__global__ __launch_bounds__(256) void reduce4_k(const u16* __restrict__ P, float* __restrict__ out) {
    int i = blockIdx.x * 256 + threadIdx.x;   // one us8 (8 elems) per thread
    const size_t stride = (size_t)2048 * 2048;
    us8 a = ((const us8*)P)[i];
    us8 b = ((const us8*)(P + stride))[i];
    us8 c = ((const us8*)(P + 2 * stride))[i];
    us8 d = ((const us8*)(P + 3 * stride))[i];
    f32x4 lo, hi;
#pragma unroll
    for (int j = 0; j < 4; ++j) {
        lo[j] = b2f(a[j]) + b2f(b[j]) + b2f(c[j]) + b2f(d[j]);
        hi[j] = b2f(a[j + 4]) + b2f(b[j + 4]) + b2f(c[j + 4]) + b2f(d[j + 4]);
    }
    ((f32x4*)out)[2 * i] = lo;
    ((f32x4*)out)[2 * i + 1] = hi;
}

// ---------------- RMSNorm + RoPE, 16 threads/head-unit, no LDS/barriers ----------------
// unit = s*36 + u (u<32: q head u; u>=32: k head u-32). Thread lt=t&15 owns d = lt*8..lt*8+7.
// Sum-reduce via shfl_xor {1,2,4,8} within 16-lane group; RoPE partner d^64 = lane^8.
__global__ __launch_bounds__(256) void norm_rope2(const u16* __restrict__ qkv,
                                                  const u16* __restrict__ qw, const u16* __restrict__ kw,
                                                  const u16* __restrict__ cosp, const u16* __restrict__ sinp,
                                                  u16* __restrict__ qr, u16* __restrict__ kr) {
    int t = threadIdx.x;
    int unit = blockIdx.x * 16 + (t >> 4);
    int lt = t & 15;
    int s = unit / 36, u = unit - s * 36;
    int d0 = lt * 8;

    size_t src;
    if (u < 32) src = (size_t)s * NQKV + u * 256 + d0;
    else        src = (size_t)s * NQKV + 8192 + (u - 32) * 128 + d0;
    us8 xv = *(const us8*)(qkv + src);
    float x[8];
    float ss = 0.f;
#pragma unroll
    for (int i = 0; i < 8; ++i) { x[i] = b2f(xv[i]); ss += x[i] * x[i]; }
#pragma unroll
    for (int m = 1; m <= 8; m <<= 1) ss += __shfl_xor(ss, m);
    float rms = rsqrtf(ss * (1.0f / 128.0f) + 1e-6f);

    const u16* wp = (u < 32 ? qw : kw) + d0;
    us8 wv8 = *(const us8*)wp;
    float xn[8];
#pragma unroll
    for (int i = 0; i < 8; ++i) xn[i] = x[i] * rms * b2f(wv8[i]);

    float rot[8];
#pragma unroll
    for (int i = 0; i < 8; ++i) {
        float other = __shfl_xor(xn[i], 8);
        rot[i] = (lt < 8) ? -other : other;
    }
    us8 cv = *(const us8*)(cosp + s * 128 + d0);
    us8 sv = *(const us8*)(sinp + s * 128 + d0);
    us8 o;
#pragma unroll
    for (int i = 0; i < 8; ++i)
        o[i] = f2b(xn[i] * b2f(cv[i]) + rot[i] * b2f(sv[i]));

    if (u < 32) *(us8*)(qr + ((size_t)s * NH + u) * 128 + d0) = o;
    else        *(us8*)(kr + ((size_t)(u - 32) * S_LEN + s) * 128 + d0) = o;
}

// ---------------- neighbor attention + sigmoid gate (MFMA, v3: 37KB LDS, 4 blocks/CU) ----------------
// Sc (scores, f32) ALIASES the K tile: QK^T keeps accumulators in regs; Sc written only after the
// barrier at which all K reads completed; V^T overwrites Sc only after softmax's reads completed.
__global__ __launch_bounds__(256) void attn_k(const u16* __restrict__ qr, const u16* __restrict__ kr,
                                              const u16* __restrict__ qkv, const void* __restrict__ ngv,
                                              u16* __restrict__ A2) {
    int s = blockIdx.x, kv = blockIdx.y;
    int t = threadIdx.x, wv = t >> 6, lane = t & 63;
    int h16 = lane & 15, kg = lane >> 4;
    int isi64 = dtype_i64((const u32*)ngv);

    __shared__ __align__(16) char KVb[32768];   // K tile -> (Sc f32) -> V^T tile
    __shared__ __align__(16) u16 Ps[16 * 128];
    __shared__ int sidx[128];
    __shared__ float svalid[128];
    float* Sc = (float*)KVb;                    // [128][17] f32 = 8704 B, aliases K

    if (t < 128) {
        int idx;
        if (isi64) idx = (int)((const long long*)ngv)[(size_t)s * 128 + t];
        else       idx = ((const int*)ngv)[s * 128 + t];
        bool valid = (idx >= 0) && (idx <= s);
        int safe = idx < 0 ? 0 : (idx > S_LEN - 1 ? S_LEN - 1 : idx);
        sidx[t] = safe;
        svalid[t] = valid ? 1.f : 0.f;
    }
    ((us4*)Ps)[256 + t] = (us4){0, 0, 0, 0};   // zero pad rows 8..15 of P
    __syncthreads();                            // bar0: sidx ready

    // ---- stage K via global_load_lds (linear dest, pre-swizzled source column) ----
#pragma unroll
    for (int it = 0; it < 8; ++it) {
        int c = it * 256 + t;
        int j = c >> 4, slot = c & 15;
        const u16* src = kr + ((size_t)kv * S_LEN + sidx[j]) * 128 + ((slot ^ (j & 7)) * 8);
        async_copy16(src, KVb + c * 16);
    }
    const u16* qbase = qr + ((size_t)s * NH + kv * 8 + (h16 & 7)) * HEAD;
    short8 qf[4];
#pragma unroll
    for (int kk = 0; kk < 4; ++kk)
        qf[kk] = *(const short8*)(qbase + kk * 32 + kg * 8);
    __syncthreads();                            // bar1: K in LDS, Q in regs

    // ---- issue V gather (d-major, wave-uniform row, coalesced) + gate prefetch; hide under QK^T ----
    us8 vreg[8];
#pragma unroll
    for (int it = 0; it < 8; ++it) {
        int task = it * 256 + t;
        int d = task & 127, jg = task >> 7;
        const u16* vbase = qkv + 8704 + kv * 128 + d;
#pragma unroll
        for (int k = 0; k < 8; ++k)
            vreg[it][k] = vbase[(size_t)sidx[jg * 8 + k] * NQKV];
    }
    u16 greg[8];
    if (kg < 2) {
#pragma unroll
        for (int tt = 0; tt < 2; ++tt)
#pragma unroll
            for (int r = 0; r < 4; ++r)
                greg[tt * 4 + r] = qkv[(size_t)s * NQKV + (kv * 8 + kg * 4 + r) * 256 + 128 +
                                       (wv * 2 + tt) * 16 + h16];
    }

    // ---- QK^T: accumulators stay in regs (Sc aliases K; no LDS writes yet) ----
    const float scale = 0.08838834764831845f;  // 1/sqrt(128)
    f32x4 aq[2];
#pragma unroll
    for (int tt = 0; tt < 2; ++tt) {
        int nt = wv * 2 + tt;
        f32x4 a = (f32x4){0.f, 0.f, 0.f, 0.f};
#pragma unroll
        for (int kk = 0; kk < 4; ++kk) {
            short8 kf = *(const short8*)(KVb + swzoff(nt * 16 + h16, kk * 64 + kg * 16));
            a = __builtin_amdgcn_mfma_f32_16x16x32_bf16(kf, qf[kk], a, 0, 0, 0);
        }
        aq[tt] = a;
    }
    __syncthreads();                            // bar2: all K reads done (drains V+gate loads too)

    // ---- write scores over the dead K region ----
#pragma unroll
    for (int tt = 0; tt < 2; ++tt) {
        int nt = wv * 2 + tt;
#pragma unroll
        for (int r = 0; r < 4; ++r) {
            int j = nt * 16 + kg * 4 + r;
            Sc[j * 17 + h16] = (svalid[j] > 0.f) ? aq[tt][r] * scale : -1e9f;
        }
    }
    __syncthreads();                            // bar3: Sc visible

    // ---- wave-parallel softmax -> Ps ----
    {
        int h = t >> 5, g = t & 31;
        float sv[4];
#pragma unroll
        for (int q = 0; q < 4; ++q) sv[q] = Sc[(g + 32 * q) * 17 + h];
        float m = fmaxf(fmaxf(sv[0], sv[1]), fmaxf(sv[2], sv[3]));
#pragma unroll
        for (int o = 16; o; o >>= 1) m = fmaxf(m, __shfl_xor(m, o));
        float e0 = __expf(sv[0] - m), e1 = __expf(sv[1] - m);
        float e2 = __expf(sv[2] - m), e3 = __expf(sv[3] - m);
        float sum = e0 + e1 + e2 + e3;
#pragma unroll
        for (int o = 16; o; o >>= 1) sum += __shfl_xor(sum, o);
        float inv = 1.f / sum;
        *(u16*)((char*)Ps + swzoff(h, 2 * (g)))      = f2b(e0 * inv);
        *(u16*)((char*)Ps + swzoff(h, 2 * (g + 32))) = f2b(e1 * inv);
        *(u16*)((char*)Ps + swzoff(h, 2 * (g + 64))) = f2b(e2 * inv);
        *(u16*)((char*)Ps + swzoff(h, 2 * (g + 96))) = f2b(e3 * inv);
    }
    __syncthreads();                            // bar4: Ps visible; Sc reads done

    // ---- write V^T (swizzled; clobbers dead Sc) ----
#pragma unroll
    for (int it = 0; it < 8; ++it) {
        int task = it * 256 + t;
        int d = task & 127, jg = task >> 7;
        *(us8*)(KVb + swzoff(d, jg * 16)) = vreg[it];
    }
    __syncthreads();                            // bar5: V^T visible

    // ---- PV + gate ----
    short8 pf[4];
#pragma unroll
    for (int kk = 0; kk < 4; ++kk)
        pf[kk] = *(const short8*)((char*)Ps + swzoff(h16, kk * 64 + kg * 16));
#pragma unroll
    for (int tt = 0; tt < 2; ++tt) {
        int nt = wv * 2 + tt;
        f32x4 a = (f32x4){0.f, 0.f, 0.f, 0.f};
#pragma unroll
        for (int jj = 0; jj < 4; ++jj) {
            short8 vf = *(const short8*)(KVb + swzoff(nt * 16 + h16, jj * 64 + kg * 16));
            a = __builtin_amdgcn_mfma_f32_16x16x32_bf16(pf[jj], vf, a, 0, 0, 0);
        }
        int d = nt * 16 + h16;
        if (kg < 2) {
#pragma unroll
            for (int r = 0; r < 4; ++r) {
                int head = kv * 8 + kg * 4 + r;
                float gt = b2f(greg[tt * 4 + r]);
                float o = a[r] * (1.f / (1.f + __expf(-gt)));
                A2[((size_t)s * NH + head) * 128 + d] = f2b(o);
            }
        }
    }
}

extern "C" void kernel_launch(void* const* d_in, const int* in_sizes, int n_in,
                              void* d_out, int out_size, void* d_ws, size_t ws_size,
                              hipStream_t stream) {
    const void* hs = d_in[0];
    const void* Wq = d_in[1];
    const void* Wk = d_in[2];
    const void* Wv = d_in[3];
    const void* Wo = d_in[4];
    const void* qw = d_in[5];
    const void* kw = d_in[6];
    const void* cs = d_in[7];
    const void* sn = d_in[8];
    const void* ng = d_in[9];
    const u16* hsamp = (const u16*)hs;

    char* w = (char*)d_ws;
    u16* HSB = (u16*)w;
    u16* KR  = (u16*)w;
    u16* BT1 = (u16*)(w + 8388608ull);
    u16* QR  = (u16*)(w + 8388608ull);
    u16* A2  = (u16*)(w + 8388608ull + 16777216ull);
    u16* WoT = (u16*)(w + 46137344ull);
    u16* QKV = (u16*)(w + 62914560ull);            // dead after attn_k -> P (4x 8.4MB bf16 partials)
    u16* P   = QKV;
    u16* CSB = (u16*)(w + 100663296ull);
    u16* SNB = (u16*)(w + 100663296ull + 524288ull);
    u16* QWB = (u16*)(w + 100663296ull + 1048576ull);
    u16* KWB = (u16*)(w + 100663296ull + 1052672ull);

    // one prep launch: hidden conv | small-table conv | all weight transposes
    prep_k<<<10754, 256, 0, stream>>>(hs, cs, sn, qw, kw, Wq, Wk, Wv, Wo,
                                      HSB, CSB, SNB, QWB, KWB, BT1, WoT, hsamp);

    // GEMM1a: q+gate = hidden @ Wq (M=2048, N=8192, K=2048): 2D grid, 256 blocks = one 8ph round
    gemm_bt256<false><<<dim3(32, 8), 512, 0, stream>>>(HSB, BT1, QKV, 2048, 2048, 2048, NQKV, 32);
    // GEMM1b: k,v = hidden @ [Wk|Wv] (M=2048, N=1024): 128 blocks of 2ph-128^2
    gemm_bt<false><<<dim3(1024 / 128, 2048 / 128), 256, 0, stream>>>(HSB, BT1 + (size_t)8192 * 2048,
                                                                     QKV + 8192, 2048, 2048, 2048, NQKV);

    // per-head RMSNorm + rotary (16 threads/unit, no LDS)
    norm_rope2<<<4608, 256, 0, stream>>>(QKV, QWB, KWB, CSB, SNB, QR, KR);

    // neighbor attention + sigmoid gate -> A2 [2048, 4096] bf16  (QKV dead after this)
    attn_k<<<dim3(2048, 4), 256, 0, stream>>>(QR, KR, QKV, ng, A2);

    // GEMM2: out = A2 @ Wo (M=2048, N=2048, K=4096): 8ph split-K=4 folded into 2D grid (32,8)
    gemm_bt256<false><<<dim3(32, 8), 512, 0, stream>>>(A2, WoT, P, 2048, 1024, 4096, 2048, 8);
    reduce4_k<<<2048, 256, 0, stream>>>(P, (float*)d_out);
}

// Round 19
// 241.199 us; speedup vs baseline: 1.3848x; 1.0024x over previous
//
#include <hip/hip_runtime.h>
#include <hip/hip_bf16.h>

typedef unsigned short u16;
typedef unsigned int u32;
typedef __attribute__((ext_vector_type(8))) short short8;
typedef __attribute__((ext_vector_type(4))) float f32x4;
typedef __attribute__((ext_vector_type(8))) unsigned short us8;
typedef __attribute__((ext_vector_type(4))) unsigned short us4;

#define S_LEN 2048
#define NH 32
#define NKV 4
#define HEAD 128
#define NQKV 9216  // 8192 (q+gate) + 512 (k) + 512 (v)

__device__ inline float b2f(u16 u) {
    union { unsigned int i; float f; } x; x.i = ((unsigned int)u) << 16; return x.f;
}
__device__ inline u16 f2b(float f) {
    __hip_bfloat16 h = __float2bfloat16(f);
    u16 u; __builtin_memcpy(&u, &h, 2); return u;
}
__device__ inline void async_copy16(const void* g, void* l) {
    __builtin_amdgcn_global_load_lds((const __attribute__((address_space(1))) void*)g,
                                     (__attribute__((address_space(3))) void*)l, 16, 0, 0);
}
// inline dtype detection: 64-lane ballot over samples.
__device__ inline int dtype_f32(const u16* hs) {
    int lane = threadIdx.x & 63;
    u16 v = hs[2 * (lane * 32)];
    int e = (v >> 7) & 0xFF;
    unsigned long long b = __ballot(e >= 0x90);
    return __popcll(b) > 16;
}
__device__ inline int dtype_i64(const u32* ng) {
    int lane = threadIdx.x & 63;
    unsigned long long b = __ballot(ng[2 * lane + 1] == 0);
    return __popcll(b) > 48;
}
// swizzled byte offset inside a [rows][128]-bf16 LDS tile (256 B rows)
__device__ inline int swzoff(int row, int kbyte) { return row * 256 + (kbyte ^ ((row & 7) << 4)); }

#define WAITV(n) asm volatile("s_waitcnt vmcnt(" #n ")" ::: "memory")
#define WAITL()  asm volatile("s_waitcnt lgkmcnt(0)" ::: "memory")
#define BAR()    do { __builtin_amdgcn_sched_barrier(0); __builtin_amdgcn_s_barrier(); \
                      __builtin_amdgcn_sched_barrier(0); } while (0)

// ---------------- ONE prep kernel: conv_hs | conv_small(vec) | all transposes ----------------
// blocks 0..2047: hidden f32/bf16 -> bf16 (us8, 8 elems/thread)
// blocks 2048..2559: cos|sin convert (us4, 4 elems/thread)
// block  2560: qw|kw convert (scalar, 256 elems)
// blocks 2561..9216: 64x64 transpose tiles (Wq | Wk | Wv | Wo)
__global__ __launch_bounds__(256) void prep_k(const void* __restrict__ hs,
                                              const void* __restrict__ cs, const void* __restrict__ sn,
                                              const void* __restrict__ qw, const void* __restrict__ kw,
                                              const void* __restrict__ Wq, const void* __restrict__ Wk,
                                              const void* __restrict__ Wv, const void* __restrict__ Wo,
                                              u16* __restrict__ HSB, u16* __restrict__ CSB, u16* __restrict__ SNB,
                                              u16* __restrict__ QWB, u16* __restrict__ KWB,
                                              u16* __restrict__ BT1, u16* __restrict__ WoT,
                                              const u16* __restrict__ hsamp) {
    int isf = dtype_f32(hsamp);
    int b = blockIdx.x;
    int tid = threadIdx.x;
    if (b < 2048) {                               // hidden: 8 elems/thread
        int i = b * 256 + tid;                    // us8 index, 524288 total
        if (isf) {
            f32x4 lo = ((const f32x4*)hs)[2 * i];
            f32x4 hi = ((const f32x4*)hs)[2 * i + 1];
            us8 o;
#pragma unroll
            for (int j = 0; j < 4; ++j) { o[j] = f2b(lo[j]); o[j + 4] = f2b(hi[j]); }
            ((us8*)HSB)[i] = o;
        } else {
            ((us8*)HSB)[i] = ((const us8*)hs)[i];
        }
        return;
    }
    if (b < 2560) {                               // cos|sin: 4 elems/thread
        int i4 = (b - 2048) * 256 + tid;          // 0..131071
        const void* s; u16* d; int o4;
        if (i4 < 65536) { s = cs; d = CSB; o4 = i4; }
        else            { s = sn; d = SNB; o4 = i4 - 65536; }
        if (isf) {
            f32x4 v = ((const f32x4*)s)[o4];
            us4 o;
#pragma unroll
            for (int j = 0; j < 4; ++j) o[j] = f2b(v[j]);
            ((us4*)d)[o4] = o;
        } else {
            ((us4*)d)[o4] = ((const us4*)s)[o4];
        }
        return;
    }
    if (b == 2560) {                              // qw|kw: 256 scalars
        const void* s; u16* d; int off;
        if (tid < 128) { s = qw; d = QWB; off = tid; }
        else           { s = kw; d = KWB; off = tid - 128; }
        d[off] = isf ? f2b(((const float*)s)[off]) : ((const u16*)s)[off];
        return;
    }
    // transpose tiles
    int tb = b - 2561;
    __shared__ u16 t[64][68];
    const void* in; u16* out; int R, C, bx, by;
    if (tb < 4096)      { int q = tb;        in = Wq; out = BT1;                       R = 2048; C = 8192; bx = (q & 127) * 64; by = (q >> 7) * 64; }
    else if (tb < 4352) { int q = tb - 4096; in = Wk; out = BT1 + (size_t)8192 * 2048; R = 2048; C = 512;  bx = (q & 7) * 64;   by = (q >> 3) * 64; }
    else if (tb < 4608) { int q = tb - 4352; in = Wv; out = BT1 + (size_t)8704 * 2048; R = 2048; C = 512;  bx = (q & 7) * 64;   by = (q >> 3) * 64; }
    else                { int q = tb - 4608; in = Wo; out = WoT;                       R = 4096; C = 2048; bx = (q & 31) * 64;  by = (q >> 5) * 64; }
    if (isf) {
        int ch = tid & 15, r0 = tid >> 4;
#pragma unroll
        for (int p = 0; p < 4; ++p) {
            int r = r0 + p * 16;
            f32x4 v = *(const f32x4*)((const float*)in + (size_t)(by + r) * C + bx + ch * 4);
#pragma unroll
            for (int j = 0; j < 4; ++j) t[ch * 4 + j][r] = f2b(v[j]);
        }
    } else {
        int ch = tid & 7, r0 = tid >> 3;
#pragma unroll
        for (int p = 0; p < 2; ++p) {
            int r = r0 + p * 32;
            us8 v = *(const us8*)((const u16*)in + (size_t)(by + r) * C + bx + ch * 8);
#pragma unroll
            for (int j = 0; j < 8; ++j) t[ch * 8 + j][r] = v[j];
        }
    }
    __syncthreads();
    int ch = tid & 7, c0 = tid >> 3;
#pragma unroll
    for (int p = 0; p < 2; ++p) {
        int c = c0 + p * 32;
        us4 lo = *(const us4*)&t[c][ch * 8];
        us4 hi = *(const us4*)&t[c][ch * 8 + 4];
        u16* dst = out + (size_t)(bx + c) * R + by + ch * 8;
        *(us4*)dst = lo;
        *(us4*)(dst + 4) = hi;
    }
}

// ======== 256x256 8-phase GEMM (T2+T3+T4+T5): C = A[:, k0:k0+Keff] * Bt[:, k0:k0+Keff]^T ========
// 2D grid; split-K folded into x: bx = blockIdx.x % xtiles, bz = blockIdx.x / xtiles.
// k0 = bz*Keff; partials at Cc + bz*M*ldc. lda = row stride of A/Bt.
template <bool OUT_F32>
__global__ __launch_bounds__(512, 2) void gemm_bt256(const u16* __restrict__ A, const u16* __restrict__ Bt,
                                                     void* __restrict__ Cc, int M, int Keff, int lda, int ldc,
                                                     int xtiles) {
    const int bx = blockIdx.x % xtiles, bz = blockIdx.x / xtiles, by = blockIdx.y;

    __shared__ __align__(16) char lds[131072];   // [buf][A 32K | B 32K]
    const int tid = threadIdx.x, lane = tid & 63, w = tid >> 6;
    const int wm = w >> 2, wn = w & 3;
    const int l15 = lane & 15, kg = lane >> 4;
    const int lr = lane >> 3, ls = lane & 7;
    const int m0 = by * 256, n0 = bx * 256;
    const int k0 = bz * Keff;

    f32x4 acc[8][4] = {};

    auto stA = [&](int b, int kt, int beta) {
#pragma unroll
        for (int i = 0; i < 2; ++i) {
            int row_in = w * 8 + lr;                       // 0..63
            int rg = i * 128 + (beta ? 64 : 0) + row_in;   // LDS/global row
            const u16* src = A + (size_t)(m0 + rg) * lda + k0 + kt + ((ls ^ (row_in & 7)) * 8);
            char* dst = lds + b * 65536 + i * 16384 + (beta ? 8192 : 0) + w * 1024;
            async_copy16(src, dst);
        }
    };
    auto stB = [&](int b, int kt, int beta) {
#pragma unroll
        for (int i = 0; i < 2; ++i) {
            int r32 = i * 2 + (w >> 2);                    // 0..3
            int row_in = (w & 3) * 8 + lr;                 // 0..31
            int rg = r32 * 64 + (beta ? 32 : 0) + row_in;
            const u16* src = Bt + (size_t)(n0 + rg) * lda + k0 + kt + ((ls ^ (row_in & 7)) * 8);
            char* dst = lds + b * 65536 + 32768 + r32 * 8192 + (beta ? 4096 : 0) + (w & 3) * 1024;
            async_copy16(src, dst);
        }
    };
    short8 af[4][2], bf[2][2];
    auto rdA = [&](int b, int mih) {
#pragma unroll
        for (int mi = 0; mi < 4; ++mi) {
            int row = wm * 128 + (mih * 4 + mi) * 16 + l15;
#pragma unroll
            for (int ks = 0; ks < 2; ++ks)
                af[mi][ks] = *(const short8*)(lds + b * 65536 + row * 128 +
                                              ((ks * 64 + kg * 16) ^ ((l15 & 7) << 4)));
        }
    };
    auto rdB = [&](int b, int nih) {
#pragma unroll
        for (int ni = 0; ni < 2; ++ni) {
            int row = wn * 64 + (nih * 2 + ni) * 16 + l15;
#pragma unroll
            for (int ks = 0; ks < 2; ++ks)
                bf[ni][ks] = *(const short8*)(lds + b * 65536 + 32768 + row * 128 +
                                              ((ks * 64 + kg * 16) ^ ((l15 & 7) << 4)));
        }
    };
    auto mm = [&](int mih, int nih) {
        __builtin_amdgcn_s_setprio(1);
#pragma unroll
        for (int ks = 0; ks < 2; ++ks)
#pragma unroll
            for (int mi = 0; mi < 4; ++mi)
#pragma unroll
                for (int ni = 0; ni < 2; ++ni)
                    acc[mih * 4 + mi][nih * 2 + ni] = __builtin_amdgcn_mfma_f32_16x16x32_bf16(
                        af[mi][ks], bf[ni][ks], acc[mih * 4 + mi][nih * 2 + ni], 0, 0, 0);
        __builtin_amdgcn_s_setprio(0);
        __builtin_amdgcn_sched_barrier(0);
    };

    // prologue: tile 0 -> buf 0
    stA(0, 0, 0); stB(0, 0, 0); stB(0, 0, 1); stA(0, 0, 1);
    WAITV(4); BAR();

    const int NT = Keff >> 6;
    for (int t = 0; t < NT - 1; ++t) {
        const int b = t & 1, nb = b ^ 1;
        const int kn = (t + 1) << 6;
        // p0
        rdA(b, 0); rdB(b, 0);
        stA(nb, kn, 0); stB(nb, kn, 0);
        WAITL(); WAITV(6); BAR();
        mm(0, 0);
        // p1
        rdB(b, 1);
        stB(nb, kn, 1);
        WAITL(); WAITV(6); BAR();
        mm(0, 1);
        // p2
        rdA(b, 1);
        stA(nb, kn, 1);
        WAITL(); BAR();
        mm(1, 1);
        // p3
        rdB(b, 0);
        WAITL(); WAITV(4); BAR();
        mm(1, 0);
    }
    {   // tail tile
        const int b = (NT - 1) & 1;
        rdA(b, 0); rdB(b, 0);
        WAITL(); WAITV(2); BAR();
        mm(0, 0);
        rdB(b, 1);
        WAITL(); WAITV(0); BAR();
        mm(0, 1);
        rdA(b, 1);
        WAITL(); BAR();
        mm(1, 1);
        rdB(b, 0);
        WAITL(); BAR();
        mm(1, 0);
    }

    // C/D layout: col = lane&15, row = (lane>>4)*4 + r   [m89-verified]
    size_t zoff = (size_t)bz * M * ldc;
#pragma unroll
    for (int mi = 0; mi < 8; ++mi) {
        int row_b = m0 + wm * 128 + mi * 16 + (lane >> 4) * 4;
#pragma unroll
        for (int ni = 0; ni < 4; ++ni) {
            int col = n0 + wn * 64 + ni * 16 + l15;
#pragma unroll
            for (int r = 0; r < 4; ++r) {
                size_t idx = zoff + (size_t)(row_b + r) * ldc + col;
                if (OUT_F32) ((float*)Cc)[idx] = acc[mi][ni][r];
                else         ((u16*)Cc)[idx] = f2b(acc[mi][ni][r]);
            }
        }
    }
}

// ---------------- 128x128 min-2-phase GEMM (lda/ldc-aware) ----------------
template <bool OUT_F32>
__global__ __launch_bounds__(256) void gemm_bt(const u16* __restrict__ A, const u16* __restrict__ Bt,
                                               void* __restrict__ Cc, int M, int K, int lda, int ldc) {
    __shared__ __align__(16) u16 As[2][128][32];
    __shared__ __align__(16) u16 Bs[2][128][32];
    int tid = threadIdx.x, lane = tid & 63, wv = tid >> 6;
    int wm = wv >> 1, wn = wv & 1;
    int m0 = blockIdx.y * 128, n0 = blockIdx.x * 128;
    int l15 = lane & 15, kg = lane >> 4;

    auto STAGE = [&](int buf, int kt) {
#pragma unroll
        for (int p = 0; p < 2; ++p) {
            int base = (p * 4 + wv) * 64;
            int unit = base + lane;
            int row = unit >> 2, ce = (unit & 3) << 3;
            async_copy16(A + (size_t)(m0 + row) * lda + kt + ce,
                         (char*)&As[buf][0][0] + (size_t)base * 16);
            async_copy16(Bt + (size_t)(n0 + row) * lda + kt + ce,
                         (char*)&Bs[buf][0][0] + (size_t)base * 16);
        }
    };

    f32x4 acc[4][4];
#pragma unroll
    for (int mi = 0; mi < 4; ++mi)
#pragma unroll
        for (int ni = 0; ni < 4; ++ni)
            acc[mi][ni] = (f32x4){0.f, 0.f, 0.f, 0.f};

    STAGE(0, 0);
    __syncthreads();
    int cur = 0;
    for (int kt = 0; kt < K; kt += 32) {
        if (kt + 32 < K) STAGE(cur ^ 1, kt + 32);

        short8 af[4], bfr[4];
#pragma unroll
        for (int mi = 0; mi < 4; ++mi)
            af[mi] = *(const short8*)&As[cur][wm * 64 + mi * 16 + l15][kg * 8];
#pragma unroll
        for (int ni = 0; ni < 4; ++ni)
            bfr[ni] = *(const short8*)&Bs[cur][wn * 64 + ni * 16 + l15][kg * 8];
#pragma unroll
        for (int mi = 0; mi < 4; ++mi)
#pragma unroll
            for (int ni = 0; ni < 4; ++ni)
                acc[mi][ni] = __builtin_amdgcn_mfma_f32_16x16x32_bf16(af[mi], bfr[ni], acc[mi][ni], 0, 0, 0);

        __syncthreads();
        cur ^= 1;
    }

#pragma unroll
    for (int mi = 0; mi < 4; ++mi) {
        int row_b = m0 + wm * 64 + mi * 16 + (lane >> 4) * 4;
#pragma unroll
        for (int ni = 0; ni < 4; ++ni) {
            int col = n0 + wn * 64 + ni * 16 + l15;
#pragma unroll
            for (int r = 0; r < 4; ++r) {
                size_t idx = (size_t)(row_b + r) * ldc + col;
                if (OUT_F32) ((float*)Cc)[idx] = acc[mi][ni][r];
                else         ((u16*)Cc)[idx] = f2b(acc[mi][ni][r]);
            }
        }
    }
}

// ---------------- reduce 4 bf16 split-K partials -> f32 d_out (2 positions/thread) ----------------
__global__ __launch_bounds__(256) void reduce4_k(const u16* __restrict__ P, float* __restrict__ out) {
    const size_t stride = (size_t)2048 * 2048;
#pragma unroll
    for (int h = 0; h < 2; ++h) {
        int i = blockIdx.x * 256 + threadIdx.x + h * 262144;   // us8 position
        us8 a = ((const us8*)P)[i];
        us8 b = ((const us8*)(P + stride))[i];
        us8 c = ((const us8*)(P + 2 * stride))[i];
        us8 d = ((const us8*)(P + 3 * stride))[i];
        f32x4 lo, hi;
#pragma unroll
        for (int j = 0; j < 4; ++j) {
            lo[j] = b2f(a[j]) + b2f(b[j]) + b2f(c[j]) + b2f(d[j]);
            hi[j] = b2f(a[j + 4]) + b2f(b[j + 4]) + b2f(c[j + 4]) + b2f(d[j + 4]);
        }
        ((f32x4*)out)[2 * i] = lo;
        ((f32x4*)out)[2 * i + 1] = hi;
    }
}

// ---------------- RMSNorm + RoPE, 16 threads/head-unit, no LDS/barriers ----------------
// unit = s*36 + u (u<32: q head u; u>=32: k head u-32). Thread lt=t&15 owns d = lt*8..lt*8+7.
// Sum-reduce via shfl_xor {1,2,4,8} within 16-lane group; RoPE partner d^64 = lane^8.
__global__ __launch_bounds__(256) void norm_rope2(const u16* __restrict__ qkv,
                                                  const u16* __restrict__ qw, const u16* __restrict__ kw,
                                                  const u16* __restrict__ cosp, const u16* __restrict__ sinp,
                                                  u16* __restrict__ qr, u16* __restrict__ kr) {
    int t = threadIdx.x;
    int unit = blockIdx.x * 16 + (t >> 4);
    int lt = t & 15;
    int s = unit / 36, u = unit - s * 36;
    int d0 = lt * 8;

    size_t src;
    if (u < 32) src = (size_t)s * NQKV + u * 256 + d0;
    else        src = (size_t)s * NQKV + 8192 + (u - 32) * 128 + d0;
    us8 xv = *(const us8*)(qkv + src);
    float x[8];
    float ss = 0.f;
#pragma unroll
    for (int i = 0; i < 8; ++i) { x[i] = b2f(xv[i]); ss += x[i] * x[i]; }
#pragma unroll
    for (int m = 1; m <= 8; m <<= 1) ss += __shfl_xor(ss, m);
    float rms = rsqrtf(ss * (1.0f / 128.0f) + 1e-6f);

    const u16* wp = (u < 32 ? qw : kw) + d0;
    us8 wv8 = *(const us8*)wp;
    float xn[8];
#pragma unroll
    for (int i = 0; i < 8; ++i) xn[i] = x[i] * rms * b2f(wv8[i]);

    float rot[8];
#pragma unroll
    for (int i = 0; i < 8; ++i) {
        float other = __shfl_xor(xn[i], 8);
        rot[i] = (lt < 8) ? -other : other;
    }
    us8 cv = *(const us8*)(cosp + s * 128 + d0);
    us8 sv = *(const us8*)(sinp + s * 128 + d0);
    us8 o;
#pragma unroll
    for (int i = 0; i < 8; ++i)
        o[i] = f2b(xn[i] * b2f(cv[i]) + rot[i] * b2f(sv[i]));

    if (u < 32) *(us8*)(qr + ((size_t)s * NH + u) * 128 + d0) = o;
    else        *(us8*)(kr + ((size_t)(u - 32) * S_LEN + s) * 128 + d0) = o;
}

// ---------------- neighbor attention + sigmoid gate (MFMA, v3: 37KB LDS, 4 blocks/CU) ----------------
// Sc (scores, f32) ALIASES the K tile: QK^T keeps accumulators in regs; Sc written only after the
// barrier at which all K reads completed; V^T overwrites Sc only after softmax's reads completed.
__global__ __launch_bounds__(256) void attn_k(const u16* __restrict__ qr, const u16* __restrict__ kr,
                                              const u16* __restrict__ qkv, const void* __restrict__ ngv,
                                              u16* __restrict__ A2) {
    int s = blockIdx.x, kv = blockIdx.y;
    int t = threadIdx.x, wv = t >> 6, lane = t & 63;
    int h16 = lane & 15, kg = lane >> 4;
    int isi64 = dtype_i64((const u32*)ngv);

    __shared__ __align__(16) char KVb[32768];   // K tile -> (Sc f32) -> V^T tile
    __shared__ __align__(16) u16 Ps[16 * 128];
    __shared__ int sidx[128];
    __shared__ float svalid[128];
    float* Sc = (float*)KVb;                    // [128][17] f32 = 8704 B, aliases K

    if (t < 128) {
        int idx;
        if (isi64) idx = (int)((const long long*)ngv)[(size_t)s * 128 + t];
        else       idx = ((const int*)ngv)[s * 128 + t];
        bool valid = (idx >= 0) && (idx <= s);
        int safe = idx < 0 ? 0 : (idx > S_LEN - 1 ? S_LEN - 1 : idx);
        sidx[t] = safe;
        svalid[t] = valid ? 1.f : 0.f;
    }
    ((us4*)Ps)[256 + t] = (us4){0, 0, 0, 0};   // zero pad rows 8..15 of P
    __syncthreads();                            // bar0: sidx ready

    // ---- stage K via global_load_lds (linear dest, pre-swizzled source column) ----
#pragma unroll
    for (int it = 0; it < 8; ++it) {
        int c = it * 256 + t;
        int j = c >> 4, slot = c & 15;
        const u16* src = kr + ((size_t)kv * S_LEN + sidx[j]) * 128 + ((slot ^ (j & 7)) * 8);
        async_copy16(src, KVb + c * 16);
    }
    const u16* qbase = qr + ((size_t)s * NH + kv * 8 + (h16 & 7)) * HEAD;
    short8 qf[4];
#pragma unroll
    for (int kk = 0; kk < 4; ++kk)
        qf[kk] = *(const short8*)(qbase + kk * 32 + kg * 8);
    __syncthreads();                            // bar1: K in LDS, Q in regs

    // ---- issue V gather (d-major, wave-uniform row, coalesced) + gate prefetch; hide under QK^T ----
    us8 vreg[8];
#pragma unroll
    for (int it = 0; it < 8; ++it) {
        int task = it * 256 + t;
        int d = task & 127, jg = task >> 7;
        const u16* vbase = qkv + 8704 + kv * 128 + d;
#pragma unroll
        for (int k = 0; k < 8; ++k)
            vreg[it][k] = vbase[(size_t)sidx[jg * 8 + k] * NQKV];
    }
    u16 greg[8];
    if (kg < 2) {
#pragma unroll
        for (int tt = 0; tt < 2; ++tt)
#pragma unroll
            for (int r = 0; r < 4; ++r)
                greg[tt * 4 + r] = qkv[(size_t)s * NQKV + (kv * 8 + kg * 4 + r) * 256 + 128 +
                                       (wv * 2 + tt) * 16 + h16];
    }

    // ---- QK^T: accumulators stay in regs (Sc aliases K; no LDS writes yet) ----
    const float scale = 0.08838834764831845f;  // 1/sqrt(128)
    f32x4 aq[2];
#pragma unroll
    for (int tt = 0; tt < 2; ++tt) {
        int nt = wv * 2 + tt;
        f32x4 a = (f32x4){0.f, 0.f, 0.f, 0.f};
#pragma unroll
        for (int kk = 0; kk < 4; ++kk) {
            short8 kf = *(const short8*)(KVb + swzoff(nt * 16 + h16, kk * 64 + kg * 16));
            a = __builtin_amdgcn_mfma_f32_16x16x32_bf16(kf, qf[kk], a, 0, 0, 0);
        }
        aq[tt] = a;
    }
    __syncthreads();                            // bar2: all K reads done (drains V+gate loads too)

    // ---- write scores over the dead K region ----
#pragma unroll
    for (int tt = 0; tt < 2; ++tt) {
        int nt = wv * 2 + tt;
#pragma unroll
        for (int r = 0; r < 4; ++r) {
            int j = nt * 16 + kg * 4 + r;
            Sc[j * 17 + h16] = (svalid[j] > 0.f) ? aq[tt][r] * scale : -1e9f;
        }
    }
    __syncthreads();                            // bar3: Sc visible

    // ---- wave-parallel softmax -> Ps ----
    {
        int h = t >> 5, g = t & 31;
        float sv[4];
#pragma unroll
        for (int q = 0; q < 4; ++q) sv[q] = Sc[(g + 32 * q) * 17 + h];
        float m = fmaxf(fmaxf(sv[0], sv[1]), fmaxf(sv[2], sv[3]));
#pragma unroll
        for (int o = 16; o; o >>= 1) m = fmaxf(m, __shfl_xor(m, o));
        float e0 = __expf(sv[0] - m), e1 = __expf(sv[1] - m);
        float e2 = __expf(sv[2] - m), e3 = __expf(sv[3] - m);
        float sum = e0 + e1 + e2 + e3;
#pragma unroll
        for (int o = 16; o; o >>= 1) sum += __shfl_xor(sum, o);
        float inv = 1.f / sum;
        *(u16*)((char*)Ps + swzoff(h, 2 * (g)))      = f2b(e0 * inv);
        *(u16*)((char*)Ps + swzoff(h, 2 * (g + 32))) = f2b(e1 * inv);
        *(u16*)((char*)Ps + swzoff(h, 2 * (g + 64))) = f2b(e2 * inv);
        *(u16*)((char*)Ps + swzoff(h, 2 * (g + 96))) = f2b(e3 * inv);
    }
    __syncthreads();                            // bar4: Ps visible; Sc reads done

    // ---- write V^T (swizzled; clobbers dead Sc) ----
#pragma unroll
    for (int it = 0; it < 8; ++it) {
        int task = it * 256 + t;
        int d = task & 127, jg = task >> 7;
        *(us8*)(KVb + swzoff(d, jg * 16)) = vreg[it];
    }
    __syncthreads();                            // bar5: V^T visible

    // ---- PV + gate ----
    short8 pf[4];
#pragma unroll
    for (int kk = 0; kk < 4; ++kk)
        pf[kk] = *(const short8*)((char*)Ps + swzoff(h16, kk * 64 + kg * 16));
#pragma unroll
    for (int tt = 0; tt < 2; ++tt) {
        int nt = wv * 2 + tt;
        f32x4 a = (f32x4){0.f, 0.f, 0.f, 0.f};
#pragma unroll
        for (int jj = 0; jj < 4; ++jj) {
            short8 vf = *(const short8*)(KVb + swzoff(nt * 16 + h16, jj * 64 + kg * 16));
            a = __builtin_amdgcn_mfma_f32_16x16x32_bf16(pf[jj], vf, a, 0, 0, 0);
        }
        int d = nt * 16 + h16;
        if (kg < 2) {
#pragma unroll
            for (int r = 0; r < 4; ++r) {
                int head = kv * 8 + kg * 4 + r;
                float gt = b2f(greg[tt * 4 + r]);
                float o = a[r] * (1.f / (1.f + __expf(-gt)));
                A2[((size_t)s * NH + head) * 128 + d] = f2b(o);
            }
        }
    }
}

extern "C" void kernel_launch(void* const* d_in, const int* in_sizes, int n_in,
                              void* d_out, int out_size, void* d_ws, size_t ws_size,
                              hipStream_t stream) {
    const void* hs = d_in[0];
    const void* Wq = d_in[1];
    const void* Wk = d_in[2];
    const void* Wv = d_in[3];
    const void* Wo = d_in[4];
    const void* qw = d_in[5];
    const void* kw = d_in[6];
    const void* cs = d_in[7];
    const void* sn = d_in[8];
    const void* ng = d_in[9];
    const u16* hsamp = (const u16*)hs;

    char* w = (char*)d_ws;
    u16* HSB = (u16*)w;
    u16* KR  = (u16*)w;
    u16* BT1 = (u16*)(w + 8388608ull);
    u16* QR  = (u16*)(w + 8388608ull);
    u16* A2  = (u16*)(w + 8388608ull + 16777216ull);
    u16* WoT = (u16*)(w + 46137344ull);
    u16* QKV = (u16*)(w + 62914560ull);            // dead after attn_k -> P (4x 8.4MB bf16 partials)
    u16* P   = QKV;
    u16* CSB = (u16*)(w + 100663296ull);
    u16* SNB = (u16*)(w + 100663296ull + 524288ull);
    u16* QWB = (u16*)(w + 100663296ull + 1048576ull);
    u16* KWB = (u16*)(w + 100663296ull + 1052672ull);

    // one prep launch: hidden conv | cos/sin vec conv | qw/kw | all weight transposes
    prep_k<<<9217, 256, 0, stream>>>(hs, cs, sn, qw, kw, Wq, Wk, Wv, Wo,
                                     HSB, CSB, SNB, QWB, KWB, BT1, WoT, hsamp);

    // GEMM1a: q+gate = hidden @ Wq (M=2048, N=8192, K=2048): 2D grid, 256 blocks = one 8ph round
    gemm_bt256<false><<<dim3(32, 8), 512, 0, stream>>>(HSB, BT1, QKV, 2048, 2048, 2048, NQKV, 32);
    // GEMM1b: k,v = hidden @ [Wk|Wv] (M=2048, N=1024): 128 blocks of 2ph-128^2
    gemm_bt<false><<<dim3(1024 / 128, 2048 / 128), 256, 0, stream>>>(HSB, BT1 + (size_t)8192 * 2048,
                                                                     QKV + 8192, 2048, 2048, 2048, NQKV);

    // per-head RMSNorm + rotary (16 threads/unit, no LDS)
    norm_rope2<<<4608, 256, 0, stream>>>(QKV, QWB, KWB, CSB, SNB, QR, KR);

    // neighbor attention + sigmoid gate -> A2 [2048, 4096] bf16  (QKV dead after this)
    attn_k<<<dim3(2048, 4), 256, 0, stream>>>(QR, KR, QKV, ng, A2);

    // GEMM2: out = A2 @ Wo (M=2048, N=2048, K=4096): 8ph split-K=4 folded into 2D grid (32,8)
    gemm_bt256<false><<<dim3(32, 8), 512, 0, stream>>>(A2, WoT, P, 2048, 1024, 4096, 2048, 8);
    reduce4_k<<<1024, 256, 0, stream>>>(P, (float*)d_out);
}